// Round 2
// 528.283 us; speedup vs baseline: 1.0344x; 1.0344x over previous
//
#include <hip/hip_runtime.h>

// out[k][n][d] = x[n][d] - c[k][d]
// N=65536, K=32, D=64. Output 536.9 MB fp32 -> write-bandwidth-bound.
//
// Structure: LINEAR output streaming (like fillBufferAligned, which hits
// 6.25 TB/s on this exact buffer). k is derived from the linear index
// instead of looping k per thread -- the old per-thread k-loop issued 32
// stores strided by exactly 16 MiB (same L2 set every time -> set-conflict
// thrash, ~2.7 TB/s). x re-reads across k hit per-XCD L2: blocks b and
// b+512 share an x-chunk and 512 % 8 == 0 keeps them on the same XCD;
// per-XCD x slice = 2.1 MB < 4 MiB L2. Nontemporal stores keep the 537 MB
// write stream from evicting x.
//
// NOTE: __builtin_nontemporal_store needs a native clang vector type, not
// HIP_vector_type<float,4> -- hence the ext_vector_type alias + casts.

#define NPTS 65536
#define KC   32
#define D4   16                       // float4 per row (D=64)
#define PLANE (NPTS * D4)             // 2^20 float4 per k-plane
#define PER_THREAD 8
#define BLOCK 256
#define CHUNK (BLOCK * PER_THREAD)    // 2048 contiguous float4 per block

typedef float f4 __attribute__((ext_vector_type(4)));

__global__ __launch_bounds__(BLOCK) void kmeans_diff_kernel(
    const f4* __restrict__ x,         // [N, D4]
    const f4* __restrict__ c,         // [K, D4]
    f4* __restrict__ out)             // [K, N, D4] viewed linearly
{
    // Linear float4 index into out. Max = 2^25, fits in int.
    const int base = blockIdx.x * CHUNK + threadIdx.x;

    // CHUNK (2048) divides PLANE (2^20): k and d4 are constant per thread
    // across all PER_THREAD iterations (stride BLOCK=256 preserves low 4 bits
    // and never crosses a plane boundary within a block).
    const int k   = base >> 20;            // plane index
    const int d4  = base & (D4 - 1);
    const int idx0 = base & (PLANE - 1);   // x index within plane

    const f4 cv = c[(k << 4) | d4];        // wave-uniform-ish load, L1-broadcast

#pragma unroll
    for (int t = 0; t < PER_THREAD; ++t) {
        const f4 xv = x[idx0 + t * BLOCK]; // L2-resident re-reads
        const f4 o  = xv - cv;
        __builtin_nontemporal_store(o, &out[base + t * BLOCK]);
    }
}

extern "C" void kernel_launch(void* const* d_in, const int* in_sizes, int n_in,
                              void* d_out, int out_size, void* d_ws, size_t ws_size,
                              hipStream_t stream) {
    const f4* x = reinterpret_cast<const f4*>(d_in[0]);   // input_x   [N, D]
    const f4* c = reinterpret_cast<const f4*>(d_in[1]);   // centroid  [K, D]
    f4* out = reinterpret_cast<f4*>(d_out);               // [K, N, D]

    const int total = KC * PLANE;               // 33,554,432 float4
    const int grid = total / CHUNK;             // 16,384 blocks

    kmeans_diff_kernel<<<grid, BLOCK, 0, stream>>>(x, c, out);
}